// Round 10
// baseline (75.210 us; speedup 1.0000x reference)
//
#include <hip/hip_runtime.h>

// Problem constants (fixed by reference)
constexpr int B = 4, T = 8, V = 256, F = 64;
constexpr int BT = B * T;            // 32 (b,t) slices
constexpr int CHUNK = 4;             // rows of i per block
constexpr int JTILE = 4;             // columns per thread (j = lane + 64*jt)
constexpr int NCHUNK = V / CHUNK;    // 64 -> grid = 2048 single-wave blocks
constexpr int NXCD = 8;
constexpr int K4 = F / 4;            // 16 float4 chunks per row

typedef float v2f __attribute__((ext_vector_type(2)));

// R15 — rows from REGISTERS via readlane; zero row memory traffic.
// Falsification matrix so far: fetch volume exact (R12), HBM idle during
// kernel (196 GB/s), write-allocate negligible, LDS path costs ~10us/CU of
// pipe serialization (R9/R11), TLP saturates at 4 waves/SIMD (R12/R13),
// ILP substitutes for TLP but hits the same ~28us floor (R14), VALU issue
// floor 2.6us, VALUBusy 17%. Last shared serializer: in-loop row operands
// on the SMEM path — 128 s_load_dwordx4 can't fit SGPRs, so the compiler
// consumes them in small batches, each forcing s_waitcnt lgkmcnt(0) FULL
// drain (SMEM returns out-of-order; no fine counting) -> ~16-32 serial
// latency epochs per wave that neither TLP nor ILP can overlap away.
// Fix: row i IS column i, already in the owning lane's registers. In the
// R14 single-wave layout, rows i0..i0+3 live in lane (i0&63)+r of register
// slot ic>>4 (uniform across r since i0%4==0). Broadcast via
// __builtin_amdgcn_readlane (VALU->SGPR, no memory, no waitcnt); slot is
// wave-uniform -> 4-way uniform branch to template bodies (no divergence).
// Inner loop = coalesced col loads (unroll-4 prefetch) + pure VALU.
// History: R6 packed math (kept). R7 transpose: neutral. R8 forced bound:
// spills. R9/R11 LDS rowbuf: LDS-pipe cost. R10 XCD swizzle: neutral,
// kept. R12 diagnostic 2x. R13 TLP x2: neutral. R14 ILP x4: neutral.
__device__ __forceinline__ float rdl(float v, int lane)
{
    return __int_as_float(__builtin_amdgcn_readlane(__float_as_int(v), lane));
}

template<int SLOT>
__device__ __forceinline__ void body(const float* __restrict__ xbt,
                                     const float4* __restrict__ a4,
                                     int i0, int t, float* __restrict__ ob)
{
    const float4* cp0 = reinterpret_cast<const float4*>(xbt + (size_t)(t      ) * F);
    const float4* cp1 = reinterpret_cast<const float4*>(xbt + (size_t)(t +  64) * F);
    const float4* cp2 = reinterpret_cast<const float4*>(xbt + (size_t)(t + 128) * F);
    const float4* cp3 = reinterpret_cast<const float4*>(xbt + (size_t)(t + 192) * F);
    const int rl0 = i0 & 63;               // owning lane of row i0 (uniform)

    v2f acc[CHUNK][JTILE];
#pragma unroll
    for (int r = 0; r < CHUNK; ++r)
#pragma unroll
        for (int jt = 0; jt < JTILE; ++jt) acc[r][jt] = (v2f){0.0f, 0.0f};

#pragma unroll 4
    for (int k = 0; k < K4; ++k) {
        const float4 xv0 = cp0[k], xv1 = cp1[k], xv2 = cp2[k], xv3 = cp3[k];
        const float4 av  = a4[k];          // uniform, loop-inv -> SGPR hoist
        const v2f alo = (v2f){av.x, av.y};
        const v2f ahi = (v2f){av.z, av.w};
        const v2f xlo[JTILE] = {{xv0.x, xv0.y}, {xv1.x, xv1.y},
                                {xv2.x, xv2.y}, {xv3.x, xv3.y}};
        const v2f xhi[JTILE] = {{xv0.z, xv0.w}, {xv1.z, xv1.w},
                                {xv2.z, xv2.w}, {xv3.z, xv3.w}};
        // row source = the slot holding columns [64*SLOT, 64*SLOT+64)
        const float4 xs = (SLOT == 0) ? xv0 : (SLOT == 1) ? xv1
                        : (SLOT == 2) ? xv2 : xv3;
#pragma unroll
        for (int r = 0; r < CHUNK; ++r) {
            const int rl = rl0 + r;        // runtime-uniform lane index
            const v2f slo = (v2f){rdl(xs.x, rl), rdl(xs.y, rl)};
            const v2f shi = (v2f){rdl(xs.z, rl), rdl(xs.w, rl)};
#pragma unroll
            for (int jt = 0; jt < JTILE; ++jt) {
                const v2f d0 = xlo[jt] - slo;      // v_pk_add (neg mod)
                const v2f d1 = xhi[jt] - shi;
                const v2f b0 = __builtin_elementwise_max(d0, -d0);  // v_pk_max
                const v2f b1 = __builtin_elementwise_max(d1, -d1);
                acc[r][jt] = __builtin_elementwise_fma(b0, alo, acc[r][jt]);
                acc[r][jt] = __builtin_elementwise_fma(b1, ahi, acc[r][jt]);
            }
        }
    }

    float tmp[CHUNK][JTILE];
#pragma unroll
    for (int r = 0; r < CHUNK; ++r)
#pragma unroll
        for (int jt = 0; jt < JTILE; ++jt) {
            const float s = acc[r][jt].x + acc[r][jt].y;
            tmp[r][jt] = __expf(fmaxf(s, 0.0f));
        }

    // wave-local butterfly ALLREDUCE per row (symmetry: row sum = denom);
    // no LDS, no barriers.
#pragma unroll
    for (int r = 0; r < CHUNK; ++r) {
        float p = (tmp[r][0] + tmp[r][1]) + (tmp[r][2] + tmp[r][3]);
        p += __shfl_xor(p, 32);
        p += __shfl_xor(p, 16);
        p += __shfl_xor(p, 8);
        p += __shfl_xor(p, 4);
        p += __shfl_xor(p, 2);
        p += __shfl_xor(p, 1);
        const float rd = 1.0f / p;
#pragma unroll
        for (int jt = 0; jt < JTILE; ++jt)
            ob[(size_t)r * V + jt * 64 + t] = tmp[r][jt] * rd;
    }
}

__global__ __launch_bounds__(64)
void gl_fused(const float* __restrict__ X, const float* __restrict__ A,
              float* __restrict__ OUT)
{
    const int t = threadIdx.x;             // lane 0..63
    // XCD swizzle: consecutive logical blocks (same bt) pinned to one XCD
    const int lb  = (blockIdx.x & (NXCD - 1)) * (BT * NCHUNK / NXCD)
                  + (blockIdx.x >> 3);
    const int bt  = lb >> 6;               // / NCHUNK (=64)
    const int ic  = lb & (NCHUNK - 1);
    const int i0  = ic * CHUNK;

    const float* xbt = X + (size_t)bt * V * F;
    const float4* a4 = reinterpret_cast<const float4*>(A);
    float* ob = OUT + (((size_t)bt * V + i0) * V);

    switch (ic >> 4) {                     // wave-uniform: no divergence
        case 0: body<0>(xbt, a4, i0, t, ob); break;
        case 1: body<1>(xbt, a4, i0, t, ob); break;
        case 2: body<2>(xbt, a4, i0, t, ob); break;
        default: body<3>(xbt, a4, i0, t, ob); break;
    }
}

extern "C" void kernel_launch(void* const* d_in, const int* in_sizes, int n_in,
                              void* d_out, int out_size, void* d_ws, size_t ws_size,
                              hipStream_t stream)
{
    const float* X = (const float*)d_in[0];   // [B,T,V,F] fp32
    const float* A = (const float*)d_in[1];   // [F,1]     fp32
    float* OUT = (float*)d_out;               // [B,T,V,V] fp32

    dim3 grid(BT * NCHUNK), block(64);
    gl_fused<<<grid, block, 0, stream>>>(X, A, OUT);
}

// Round 11
// 72.399 us; speedup vs baseline: 1.0388x; 1.0388x over previous
//
#include <hip/hip_runtime.h>

// Problem constants (fixed by reference)
constexpr int B = 4, T = 8, V = 256, F = 64;
constexpr int BT = B * T;            // 32 (b,t) slices
constexpr int CHUNK = 8;             // rows of i per block (proven sweet spot)
constexpr int NCHUNK = V / CHUNK;    // 32 -> grid = 1024 blocks (4/CU, 4 rounds)
constexpr int NXCD = 8;
constexpr int K4 = F / 4;            // 16 float4 chunks per row

typedef float v2f __attribute__((ext_vector_type(2)));

// R16 — collapse the per-wave COLD-MISS SERIAL CHAIN.
// Model that finally fits all data: kernel ~= rounds(4 blocks/CU) x
// per-wave critical path. Issue is ~1.7us/wave; the other ~4us is the
// wave's 16KB of column lines, HBM-cold every iteration (fill poisons
// L2/L3), fetched in ~8 register-limited serial batches (~900cyc each)
// because the k-loop consumes loads windowed. Fix: preload the WHOLE
// column (16 float4 = 64 VGPR) in ONE batch at kernel top, pinned with
// sched_barrier(0) so nothing sinks into it -> 256 cold lines in flight
// at once, one round trip. Rows stay s_load (proven fine); 'a' moves to
// in-loop uniform reads (SGPR-resident, R13-proven) to fund the VGPRs.
// Target ~110 VGPR -> 4 waves/SIMD, same occupancy as the 71.85us R10.
//
// Falsified so far: coalescing (R7), occupancy force (R8: spills),
// LDS rows (R9/R11: LDS-pipe cost), XCD locality (R10: neutral, kept),
// over-fetch/BW/write-allocate (R12: FETCH=X exactly, 196GB/s),
// TLP (R13), ILP (R14), SMEM row drains (R15: readlane, neutral).
__global__ __launch_bounds__(256)
void gl_fused(const float* __restrict__ X, const float* __restrict__ A,
              float* __restrict__ OUT)
{
    const int tid = threadIdx.x;           // column j
    // XCD swizzle: consecutive logical blocks (same bt) pinned to one XCD
    const int lb  = (blockIdx.x & (NXCD - 1)) * (BT * NCHUNK / NXCD)
                  + (blockIdx.x >> 3);
    const int bt  = lb >> 5;               // / NCHUNK
    const int ic  = lb & (NCHUNK - 1);
    const int i0  = ic * CHUNK;

    const float* xbt = X + (size_t)bt * V * F;            // [256][64] tile
    const float4* xrow4 = reinterpret_cast<const float4*>(xbt + (size_t)i0 * F);
    const float4* a4    = reinterpret_cast<const float4*>(A);   // uniform

    __shared__ float wpart[4][CHUNK];      // per-wave partial row sums
    __shared__ float rden[CHUNK];          // reciprocal denominators

    // ---- R16: issue ALL column loads up front (one cold round trip) ----
    float4 colv[K4];                       // 64 VGPR
    const float4* colp = reinterpret_cast<const float4*>(xbt + (size_t)tid * F);
#pragma unroll
    for (int k = 0; k < K4; ++k)
        colv[k] = colp[k];
    __builtin_amdgcn_sched_barrier(0);     // keep loads above the compute

    v2f acc2[CHUNK];
#pragma unroll
    for (int r = 0; r < CHUNK; ++r) acc2[r] = (v2f){0.0f, 0.0f};

#pragma unroll
    for (int k = 0; k < K4; ++k) {
        const float4 xv = colv[k];
        const float4 av = a4[k];           // uniform, loop-inv -> SGPRs
        const v2f xlo = (v2f){xv.x, xv.y};
        const v2f xhi = (v2f){xv.z, xv.w};
        const v2f alo = (v2f){av.x, av.y};
        const v2f ahi = (v2f){av.z, av.w};
#pragma unroll
        for (int r = 0; r < CHUNK; ++r) {
            const float4 sr = xrow4[r * K4 + k];    // uniform -> s_load_dwordx4
            const v2f d0 = xlo - (v2f){sr.x, sr.y}; // v_pk_add (neg mod)
            const v2f d1 = xhi - (v2f){sr.z, sr.w};
            const v2f a0 = __builtin_elementwise_max(d0, -d0);  // v_pk_max
            const v2f a1 = __builtin_elementwise_max(d1, -d1);
            acc2[r] = __builtin_elementwise_fma(a0, alo, acc2[r]); // v_pk_fma
            acc2[r] = __builtin_elementwise_fma(a1, ahi, acc2[r]);
        }
    }

    float tmp[CHUNK];
#pragma unroll
    for (int r = 0; r < CHUNK; ++r) {
        const float s = acc2[r].x + acc2[r].y;
        tmp[r] = __expf(fmaxf(s, 0.0f));
    }

    // block reduction: row sum = denominator (symmetry)
    const int lane = tid & 63;
    const int wv   = tid >> 6;
#pragma unroll
    for (int r = 0; r < CHUNK; ++r) {
        float v = tmp[r];
        v += __shfl_xor(v, 32);
        v += __shfl_xor(v, 16);
        v += __shfl_xor(v, 8);
        v += __shfl_xor(v, 4);
        v += __shfl_xor(v, 2);
        v += __shfl_xor(v, 1);
        if (lane == 0) wpart[wv][r] = v;
    }
    __syncthreads();
    if (tid < CHUNK) {
        const float d = wpart[0][tid] + wpart[1][tid] + wpart[2][tid] + wpart[3][tid];
        rden[tid] = 1.0f / d;
    }
    __syncthreads();

    // S[bt, i0+r, tid] = tmp[r] / denom[i0+r]; consecutive tids -> coalesced
    float* obase = OUT + (((size_t)bt * V + i0) * V) + tid;
#pragma unroll
    for (int r = 0; r < CHUNK; ++r)
        obase[(size_t)r * V] = tmp[r] * rden[r];
}

extern "C" void kernel_launch(void* const* d_in, const int* in_sizes, int n_in,
                              void* d_out, int out_size, void* d_ws, size_t ws_size,
                              hipStream_t stream)
{
    const float* X = (const float*)d_in[0];   // [B,T,V,F] fp32
    const float* A = (const float*)d_in[1];   // [F,1]     fp32
    float* OUT = (float*)d_out;               // [B,T,V,V] fp32

    dim3 grid(BT * NCHUNK), block(256);
    gl_fused<<<grid, block, 0, stream>>>(X, A, OUT);
}